// Round 1
// baseline (550.613 us; speedup 1.0000x reference)
//
#include <hip/hip_runtime.h>
#include <cstdint>

// Attention block: x(B=64,T=128,C=2048) fp32; H=16, hd=128.
// q=x@wq^T, k=x@wk^T, v=x@wv^T ; RoPE(q,k) ; causal softmax attn ; out@wo^T.
// Strategy: bf16 MFMA everywhere (threshold allows), fp32 softmax.

typedef unsigned short ushort;
typedef __bf16 bf16x8 __attribute__((ext_vector_type(8)));
typedef float floatx4 __attribute__((ext_vector_type(4)));

__device__ __forceinline__ ushort f2bf(float f) {
  union { float f; uint32_t u; } v; v.f = f;
  uint32_t r = v.u + 0x7FFFu + ((v.u >> 16) & 1u);
  return (ushort)(r >> 16);
}
__device__ __forceinline__ float bf2f(ushort h) {
  union { uint32_t u; float f; } v; v.u = ((uint32_t)h) << 16;
  return v.f;
}

// global -> LDS direct copy, 16B per lane. LDS dest must be wave-uniform base;
// HW adds lane*16. Integer-cast idiom for address spaces (generic LDS ptr low
// 32 bits == LDS offset on amdgcn).
__device__ __forceinline__ void load_lds16(const void* g, void* l) {
  __builtin_amdgcn_global_load_lds(
      (__attribute__((address_space(1))) void*)(uintptr_t)g,
      (__attribute__((address_space(3))) void*)(uint32_t)(uintptr_t)l,
      16, 0, 0);
}

__device__ __forceinline__ void store_out(ushort* C, size_t i, float v) { C[i] = f2bf(v); }
__device__ __forceinline__ void store_out(float* C, size_t i, float v) { C[i] = v; }

// C[m,n] = sum_k A[m,k]*B[n,k].  A: M x K bf16 row-major, B: N x K bf16 row-major.
// m97 recipe: 128x128 tile, BK=32, 256 thr = 4 waves (2x2 of 64x64), 4x4 MFMA acc.
template <typename OutT>
__device__ __forceinline__ void gemm_bt_body(const ushort* __restrict__ A,
                                             const ushort* __restrict__ B,
                                             OutT* __restrict__ C,
                                             int M, int N, int K) {
  __shared__ __align__(16) ushort As[128 * 32];
  __shared__ __align__(16) ushort Bs[128 * 32];
  const int tid = threadIdx.x;
  const int wave = tid >> 6, lane = tid & 63;
  const int quad = lane >> 4, colv = lane & 15;
  const int m0 = blockIdx.x * 128, n0 = blockIdx.y * 128;
  const int wm = (wave & 1) * 64, wn = (wave >> 1) * 64;

  floatx4 acc[4][4] = {};

  const int e0 = tid * 8;            // this thread's element index in the 128x32 tile
  const int row0 = e0 >> 5;          // 32 elems per row
  const int c0 = e0 & 31;

  for (int k0 = 0; k0 < K; k0 += 32) {
    if (k0) __syncthreads();
    const ushort* Ab = A + (size_t)(m0 + row0) * K + k0 + c0;
    const ushort* Bb = B + (size_t)(n0 + row0) * K + k0 + c0;
    // tile = 8KB = 256 thr * 16B * 2 calls; call j covers rows [j*64, j*64+64)
    load_lds16(Ab, &As[wave * 512]);
    load_lds16(Bb, &Bs[wave * 512]);
    load_lds16(Ab + (size_t)64 * K, &As[wave * 512 + 2048]);
    load_lds16(Bb + (size_t)64 * K, &Bs[wave * 512 + 2048]);
    __syncthreads();

    bf16x8 af[4], bfr[4];
#pragma unroll
    for (int i = 0; i < 4; ++i)
      af[i] = *(const bf16x8*)&As[(wm + i * 16 + colv) * 32 + quad * 8];
#pragma unroll
    for (int j = 0; j < 4; ++j)
      bfr[j] = *(const bf16x8*)&Bs[(wn + j * 16 + colv) * 32 + quad * 8];
#pragma unroll
    for (int i = 0; i < 4; ++i)
#pragma unroll
      for (int j = 0; j < 4; ++j)
        acc[i][j] = __builtin_amdgcn_mfma_f32_16x16x32_bf16(af[i], bfr[j], acc[i][j], 0, 0, 0);
  }

  // C/D layout: row = quad*4 + r, col = lane&15 (m89-verified)
#pragma unroll
  for (int i = 0; i < 4; ++i)
#pragma unroll
    for (int j = 0; j < 4; ++j)
#pragma unroll
      for (int r = 0; r < 4; ++r) {
        int m = m0 + wm + i * 16 + quad * 4 + r;
        int n = n0 + wn + j * 16 + colv;
        store_out(C, (size_t)m * N + n, acc[i][j][r]);
      }
}

__global__ __launch_bounds__(256) void gemm_qkv(
    const ushort* __restrict__ A, const ushort* __restrict__ Wq,
    const ushort* __restrict__ Wk, const ushort* __restrict__ Wv,
    ushort* __restrict__ Q, ushort* __restrict__ Kb, ushort* __restrict__ V) {
  const ushort* B = (blockIdx.z == 0) ? Wq : (blockIdx.z == 1) ? Wk : Wv;
  ushort* C = (blockIdx.z == 0) ? Q : (blockIdx.z == 1) ? Kb : V;
  gemm_bt_body<ushort>(A, B, C, 8192, 2048, 2048);
}

__global__ __launch_bounds__(256) void gemm_out_k(
    const ushort* __restrict__ A, const ushort* __restrict__ B,
    float* __restrict__ C) {
  gemm_bt_body<float>(A, B, C, 8192, 2048, 2048);
}

__global__ void cvt_kernel(const float* __restrict__ in, ushort* __restrict__ out, int n4) {
  int i = blockIdx.x * blockDim.x + threadIdx.x;
  if (i >= n4) return;
  float4 v = ((const float4*)in)[i];
  ushort4 o;
  o.x = f2bf(v.x); o.y = f2bf(v.y); o.z = f2bf(v.z); o.w = f2bf(v.w);
  ((ushort4*)out)[i] = o;
}

// RoPE in place on q and k (bf16). Pair = (even,odd) within hd.
__global__ void rope_kernel(ushort* __restrict__ Q, ushort* __restrict__ K,
                            const float* __restrict__ Cf, const float* __restrict__ Sf,
                            int npairs) {
  int idx = blockIdx.x * blockDim.x + threadIdx.x;
  if (idx >= npairs) return;
  int e = idx << 1;               // flat even element index in (B,T,H,hd)
  int i = (e >> 1) & 63;          // pair index within hd (hd/2 = 64)
  int t = (e >> 11) & 127;        // e / (H*hd=2048) mod T
  float c = Cf[t * 64 + i], s = Sf[t * 64 + i];
  uint32_t qp = *(uint32_t*)&Q[e];
  float qe = bf2f((ushort)(qp & 0xFFFF)), qo = bf2f((ushort)(qp >> 16));
  *(uint32_t*)&Q[e] = (uint32_t)f2bf(qe * c - qo * s) | ((uint32_t)f2bf(qe * s + qo * c) << 16);
  uint32_t kp = *(uint32_t*)&K[e];
  float ke = bf2f((ushort)(kp & 0xFFFF)), ko = bf2f((ushort)(kp >> 16));
  *(uint32_t*)&K[e] = (uint32_t)f2bf(ke * c - ko * s) | ((uint32_t)f2bf(ke * s + ko * c) << 16);
}

// One block per (b,h). T=128, hd=128. 4 waves; wave handles 32 S/O rows.
// XOR-swizzled LDS tiles (group g of 8 elems at g^(row&15)) -> 2-way conflicts (free).
__global__ __launch_bounds__(256) void attn_kernel(
    const ushort* __restrict__ Q, const ushort* __restrict__ K,
    const ushort* __restrict__ V, ushort* __restrict__ O) {
  __shared__ __align__(16) ushort Qs[128 * 128];   // Q, then P
  __shared__ __align__(16) ushort KVs[128 * 128];  // K, then V^T
  const int b = blockIdx.x >> 4, h = blockIdx.x & 15;
  const int tid = threadIdx.x, wave = tid >> 6, lane = tid & 63;
  const int quad = lane >> 4, colv = lane & 15;
  const size_t gbase = (size_t)b * 262144 + (size_t)h * 128;  // (b, t=0, h, d=0)

#pragma unroll
  for (int sgi = 0; sgi < 8; ++sgi) {
    int seg = tid + sgi * 256;
    int t = seg >> 4, g = seg & 15;
    uint4 qv = *(const uint4*)(Q + gbase + (size_t)t * 2048 + g * 8);
    uint4 kv = *(const uint4*)(K + gbase + (size_t)t * 2048 + g * 8);
    int so = t * 128 + ((g ^ (t & 15)) << 3);
    *(uint4*)&Qs[so] = qv;
    *(uint4*)&KVs[so] = kv;
  }
  __syncthreads();

  // S = Q K^T (scaled+masked later). acc tiles: 2 (m) x 8 (n).
  floatx4 accs[2][8] = {};
#pragma unroll
  for (int kc = 0; kc < 4; ++kc) {
    bf16x8 af[2], bfr[8];
#pragma unroll
    for (int i = 0; i < 2; ++i) {
      int r = wave * 32 + i * 16 + colv;
      af[i] = *(const bf16x8*)&Qs[r * 128 + ((((kc << 2) | quad) ^ (r & 15)) << 3)];
    }
#pragma unroll
    for (int j = 0; j < 8; ++j) {
      int r = j * 16 + colv;
      bfr[j] = *(const bf16x8*)&KVs[r * 128 + ((((kc << 2) | quad) ^ (r & 15)) << 3)];
    }
#pragma unroll
    for (int i = 0; i < 2; ++i)
#pragma unroll
      for (int j = 0; j < 8; ++j)
        accs[i][j] = __builtin_amdgcn_mfma_f32_16x16x32_bf16(af[i], bfr[j], accs[i][j], 0, 0, 0);
  }

  // softmax per row, in registers. Row t lives in 16 lanes (same quad) x 8 j-tiles.
  const float scale = 0.08838834764831845f;  // 1/sqrt(128)
#pragma unroll
  for (int i = 0; i < 2; ++i)
#pragma unroll
    for (int r = 0; r < 4; ++r) {
      int t = wave * 32 + i * 16 + quad * 4 + r;
      float mx = -1e30f;
#pragma unroll
      for (int j = 0; j < 8; ++j) {
        int s = j * 16 + colv;
        float v = accs[i][j][r] * scale;
        v = (s <= t) ? v : -1e30f;
        accs[i][j][r] = v;
        mx = fmaxf(mx, v);
      }
#pragma unroll
      for (int off = 1; off < 16; off <<= 1) mx = fmaxf(mx, __shfl_xor(mx, off, 64));
      float l = 0.f;
#pragma unroll
      for (int j = 0; j < 8; ++j) {
        float p = __expf(accs[i][j][r] - mx);
        accs[i][j][r] = p;
        l += p;
      }
#pragma unroll
      for (int off = 1; off < 16; off <<= 1) l += __shfl_xor(l, off, 64);
      float inv = 1.0f / l;
#pragma unroll
      for (int j = 0; j < 8; ++j) {
        int s = j * 16 + colv;
        Qs[t * 128 + ((((s >> 3) ^ (t & 15)) << 3) | (s & 7))] = f2bf(accs[i][j][r] * inv);
      }
    }
  __syncthreads();  // all waves done with K (and own Q rows rewritten as P)

  // V -> KVs transposed: KVs[d][s] = V[s][d]
#pragma unroll
  for (int sgi = 0; sgi < 8; ++sgi) {
    int seg = tid + sgi * 256;
    int t = seg >> 4;
    int dg = (seg & 15) << 3;
    uint4 vv = *(const uint4*)(V + gbase + (size_t)t * 2048 + dg);
    const ushort* vp = (const ushort*)&vv;
#pragma unroll
    for (int jj = 0; jj < 8; ++jj) {
      int d = dg + jj;
      KVs[d * 128 + ((((t >> 3) ^ (d & 15)) << 3) | (t & 7))] = vp[jj];
    }
  }
  __syncthreads();

  // O = P V  (A = P rows t over k=s; B = V^T rows d over k=s)
  floatx4 acco[2][8] = {};
#pragma unroll
  for (int kc = 0; kc < 4; ++kc) {
    bf16x8 af[2], bfr[8];
#pragma unroll
    for (int i = 0; i < 2; ++i) {
      int r = wave * 32 + i * 16 + colv;
      af[i] = *(const bf16x8*)&Qs[r * 128 + ((((kc << 2) | quad) ^ (r & 15)) << 3)];
    }
#pragma unroll
    for (int j = 0; j < 8; ++j) {
      int r = j * 16 + colv;
      bfr[j] = *(const bf16x8*)&KVs[r * 128 + ((((kc << 2) | quad) ^ (r & 15)) << 3)];
    }
#pragma unroll
    for (int i = 0; i < 2; ++i)
#pragma unroll
      for (int j = 0; j < 8; ++j)
        acco[i][j] = __builtin_amdgcn_mfma_f32_16x16x32_bf16(af[i], bfr[j], acco[i][j], 0, 0, 0);
  }

#pragma unroll
  for (int i = 0; i < 2; ++i)
#pragma unroll
    for (int j = 0; j < 8; ++j)
#pragma unroll
      for (int r = 0; r < 4; ++r) {
        int t = wave * 32 + i * 16 + quad * 4 + r;
        int d = j * 16 + colv;
        O[gbase + (size_t)t * 2048 + d] = f2bf(acco[i][j][r]);
      }
}

extern "C" void kernel_launch(void* const* d_in, const int* in_sizes, int n_in,
                              void* d_out, int out_size, void* d_ws, size_t ws_size,
                              hipStream_t stream) {
  const float* x    = (const float*)d_in[0];
  const float* fcos = (const float*)d_in[1];
  const float* fsin = (const float*)d_in[2];
  const float* wq   = (const float*)d_in[3];
  const float* wk   = (const float*)d_in[4];
  const float* wv   = (const float*)d_in[5];
  const float* wo   = (const float*)d_in[6];
  float* out = (float*)d_out;

  const size_t CC = 2048ull * 2048ull;  // weight elems
  const size_t MC = 8192ull * 2048ull;  // activation elems (B*T x C)
  // ws layout (bf16): wob | xb (reused as attn-out) | wqb | wkb | wvb | Qb | Kb | Vb
  // total = (4*CC + 4*MC) * 2 bytes = 160 MiB
  ushort* wob = (ushort*)d_ws;
  ushort* xb  = wob + CC;
  ushort* wqb = xb + MC;
  ushort* wkb = wqb + CC;
  ushort* wvb = wkb + CC;
  ushort* Qb  = wvb + CC;
  ushort* Kb  = Qb + MC;
  ushort* Vb  = Kb + MC;

  cvt_kernel<<<dim3((unsigned)(MC / 4 / 256)), 256, 0, stream>>>(x, xb, (int)(MC / 4));
  cvt_kernel<<<dim3((unsigned)(CC / 4 / 256)), 256, 0, stream>>>(wq, wqb, (int)(CC / 4));
  cvt_kernel<<<dim3((unsigned)(CC / 4 / 256)), 256, 0, stream>>>(wk, wkb, (int)(CC / 4));
  cvt_kernel<<<dim3((unsigned)(CC / 4 / 256)), 256, 0, stream>>>(wv, wvb, (int)(CC / 4));
  cvt_kernel<<<dim3((unsigned)(CC / 4 / 256)), 256, 0, stream>>>(wo, wob, (int)(CC / 4));

  gemm_qkv<<<dim3(64, 16, 3), 256, 0, stream>>>(xb, wqb, wkb, wvb, Qb, Kb, Vb);
  rope_kernel<<<dim3((unsigned)(MC / 2 / 256)), 256, 0, stream>>>(Qb, Kb, fcos, fsin, (int)(MC / 2));
  attn_kernel<<<dim3(1024), 256, 0, stream>>>(Qb, Kb, Vb, xb /*attn out aliases xb*/);
  gemm_out_k<<<dim3(64, 16), 256, 0, stream>>>(xb, wob, out);
}

// Round 2
// 526.703 us; speedup vs baseline: 1.0454x; 1.0454x over previous
//
#include <hip/hip_runtime.h>
#include <cstdint>

// Attention block: x(B=64,T=128,C=2048) fp32; H=16, hd=128.
// q=x@wq^T, k=x@wk^T, v=x@wv^T ; RoPE(q,k) ; causal softmax attn ; out@wo^T.
// bf16 MFMA everywhere; fp32 softmax; RoPE fused into attention kernel.

typedef unsigned short ushort;
typedef __bf16 bf16x8 __attribute__((ext_vector_type(8)));
typedef float floatx4 __attribute__((ext_vector_type(4)));

__device__ __forceinline__ ushort f2bf(float f) {
  union { float f; uint32_t u; } v; v.f = f;
  uint32_t r = v.u + 0x7FFFu + ((v.u >> 16) & 1u);
  return (ushort)(r >> 16);
}
__device__ __forceinline__ float bf2f(ushort h) {
  union { uint32_t u; float f; } v; v.u = ((uint32_t)h) << 16;
  return v.f;
}

__device__ __forceinline__ void load_lds16(const void* g, void* l) {
  __builtin_amdgcn_global_load_lds(
      (__attribute__((address_space(1))) void*)(uintptr_t)g,
      (__attribute__((address_space(3))) void*)(uint32_t)(uintptr_t)l,
      16, 0, 0);
}

__device__ __forceinline__ void store_out(ushort* C, size_t i, float v) { C[i] = f2bf(v); }
__device__ __forceinline__ void store_out(float* C, size_t i, float v) { C[i] = v; }

// C[m,n] = sum_k A[m,k]*B[n,k].  m97 recipe: 128x128 tile, BK=32, 4 waves, 4x4 acc.
template <typename OutT>
__device__ __forceinline__ void gemm_bt_body(const ushort* __restrict__ A,
                                             const ushort* __restrict__ B,
                                             OutT* __restrict__ C,
                                             int M, int N, int K) {
  __shared__ __align__(16) ushort As[128 * 32];
  __shared__ __align__(16) ushort Bs[128 * 32];
  const int tid = threadIdx.x;
  const int wave = tid >> 6, lane = tid & 63;
  const int quad = lane >> 4, colv = lane & 15;
  const int m0 = blockIdx.x * 128, n0 = blockIdx.y * 128;
  const int wm = (wave & 1) * 64, wn = (wave >> 1) * 64;

  floatx4 acc[4][4] = {};

  const int e0 = tid * 8;
  const int row0 = e0 >> 5;
  const int c0 = e0 & 31;

  for (int k0 = 0; k0 < K; k0 += 32) {
    if (k0) __syncthreads();
    const ushort* Ab = A + (size_t)(m0 + row0) * K + k0 + c0;
    const ushort* Bb = B + (size_t)(n0 + row0) * K + k0 + c0;
    load_lds16(Ab, &As[wave * 512]);
    load_lds16(Bb, &Bs[wave * 512]);
    load_lds16(Ab + (size_t)64 * K, &As[wave * 512 + 2048]);
    load_lds16(Bb + (size_t)64 * K, &Bs[wave * 512 + 2048]);
    __syncthreads();

    bf16x8 af[4], bfr[4];
#pragma unroll
    for (int i = 0; i < 4; ++i)
      af[i] = *(const bf16x8*)&As[(wm + i * 16 + colv) * 32 + quad * 8];
#pragma unroll
    for (int j = 0; j < 4; ++j)
      bfr[j] = *(const bf16x8*)&Bs[(wn + j * 16 + colv) * 32 + quad * 8];
#pragma unroll
    for (int i = 0; i < 4; ++i)
#pragma unroll
      for (int j = 0; j < 4; ++j)
        acc[i][j] = __builtin_amdgcn_mfma_f32_16x16x32_bf16(af[i], bfr[j], acc[i][j], 0, 0, 0);
  }

#pragma unroll
  for (int i = 0; i < 4; ++i)
#pragma unroll
    for (int j = 0; j < 4; ++j)
#pragma unroll
      for (int r = 0; r < 4; ++r) {
        int m = m0 + wm + i * 16 + quad * 4 + r;
        int n = n0 + wn + j * 16 + colv;
        store_out(C, (size_t)m * N + n, acc[i][j][r]);
      }
}

__global__ __launch_bounds__(256) void gemm_qkv(
    const ushort* __restrict__ A, const ushort* __restrict__ Wq,
    const ushort* __restrict__ Wk, const ushort* __restrict__ Wv,
    ushort* __restrict__ Q, ushort* __restrict__ Kb, ushort* __restrict__ V) {
  const ushort* B = (blockIdx.z == 0) ? Wq : (blockIdx.z == 1) ? Wk : Wv;
  ushort* C = (blockIdx.z == 0) ? Q : (blockIdx.z == 1) ? Kb : V;
  gemm_bt_body<ushort>(A, B, C, 8192, 2048, 2048);
}

__global__ __launch_bounds__(256) void gemm_out_k(
    const ushort* __restrict__ A, const ushort* __restrict__ B,
    float* __restrict__ C) {
  gemm_bt_body<float>(A, B, C, 8192, 2048, 2048);
}

// One kernel converting all five fp32 regions to bf16.
// Layout (float4 units): [0,NX): x->xb ; then 4 weight regions of NW each.
#define NX 4194304u   /* 8192*2048/4 */
#define NW 1048576u   /* 2048*2048/4 */
__global__ void cvt_all(const float* __restrict__ x, const float* __restrict__ wq,
                        const float* __restrict__ wk, const float* __restrict__ wv,
                        const float* __restrict__ wo,
                        ushort* __restrict__ xb, ushort* __restrict__ wqb,
                        ushort* __restrict__ wkb, ushort* __restrict__ wvb,
                        ushort* __restrict__ wob) {
  uint32_t i = blockIdx.x * 256u + threadIdx.x;
  const float* src;
  ushort* dst;
  uint32_t off;
  if (i < NX) {
    src = x; dst = xb; off = i;
  } else {
    uint32_t i2 = i - NX;
    uint32_t r = i2 >> 20;      // NW = 2^20
    off = i2 & (NW - 1u);
    src = (r == 0) ? wq : (r == 1) ? wk : (r == 2) ? wv : wo;
    dst = (r == 0) ? wqb : (r == 1) ? wkb : (r == 2) ? wvb : wob;
  }
  float4 v = ((const float4*)src)[off];
  ushort4 o;
  o.x = f2bf(v.x); o.y = f2bf(v.y); o.z = f2bf(v.z); o.w = f2bf(v.w);
  ((ushort4*)dst)[off] = o;
}

// One block per (b,h). T=128, hd=128. RoPE applied to Q,K on load (fp32 math).
// XOR-swizzled LDS tiles -> 2-way conflicts (free per m136).
__global__ __launch_bounds__(256) void attn_kernel(
    const ushort* __restrict__ Q, const ushort* __restrict__ K,
    const ushort* __restrict__ V, const float* __restrict__ Cf,
    const float* __restrict__ Sf, ushort* __restrict__ O) {
  __shared__ __align__(16) ushort Qs[128 * 128];   // Q, then P
  __shared__ __align__(16) ushort KVs[128 * 128];  // K, then V^T
  const int b = blockIdx.x >> 4, h = blockIdx.x & 15;
  const int tid = threadIdx.x, wave = tid >> 6, lane = tid & 63;
  const int quad = lane >> 4, colv = lane & 15;
  const size_t gbase = (size_t)b * 262144 + (size_t)h * 128;  // (b, t=0, h, d=0)

#pragma unroll
  for (int sgi = 0; sgi < 8; ++sgi) {
    int seg = tid + sgi * 256;
    int t = seg >> 4, g = seg & 15;
    uint4 qv = *(const uint4*)(Q + gbase + (size_t)t * 2048 + g * 8);
    uint4 kv = *(const uint4*)(K + gbase + (size_t)t * 2048 + g * 8);
    // RoPE: 8 elems = 4 (even,odd) pairs; pair index = g*4+j; fp32 rotate.
    float4 cf = *(const float4*)(Cf + t * 64 + g * 4);
    float4 sf = *(const float4*)(Sf + t * 64 + g * 4);
    uint32_t* qw = (uint32_t*)&qv;
    uint32_t* kw = (uint32_t*)&kv;
#pragma unroll
    for (int j = 0; j < 4; ++j) {
      float c = (&cf.x)[j], s = (&sf.x)[j];
      uint32_t w = qw[j];
      float e = bf2f((ushort)(w & 0xFFFF)), o = bf2f((ushort)(w >> 16));
      qw[j] = (uint32_t)f2bf(e * c - o * s) | ((uint32_t)f2bf(e * s + o * c) << 16);
      w = kw[j];
      e = bf2f((ushort)(w & 0xFFFF)); o = bf2f((ushort)(w >> 16));
      kw[j] = (uint32_t)f2bf(e * c - o * s) | ((uint32_t)f2bf(e * s + o * c) << 16);
    }
    int so = t * 128 + ((g ^ (t & 15)) << 3);
    *(uint4*)&Qs[so] = qv;
    *(uint4*)&KVs[so] = kv;
  }
  __syncthreads();

  // S = Q K^T. acc tiles: 2 (m) x 8 (n).
  floatx4 accs[2][8] = {};
#pragma unroll
  for (int kc = 0; kc < 4; ++kc) {
    bf16x8 af[2], bfr[8];
#pragma unroll
    for (int i = 0; i < 2; ++i) {
      int r = wave * 32 + i * 16 + colv;
      af[i] = *(const bf16x8*)&Qs[r * 128 + ((((kc << 2) | quad) ^ (r & 15)) << 3)];
    }
#pragma unroll
    for (int j = 0; j < 8; ++j) {
      int r = j * 16 + colv;
      bfr[j] = *(const bf16x8*)&KVs[r * 128 + ((((kc << 2) | quad) ^ (r & 15)) << 3)];
    }
#pragma unroll
    for (int i = 0; i < 2; ++i)
#pragma unroll
      for (int j = 0; j < 8; ++j)
        accs[i][j] = __builtin_amdgcn_mfma_f32_16x16x32_bf16(af[i], bfr[j], accs[i][j], 0, 0, 0);
  }

  // softmax per row in registers. Row t = 16 lanes (same quad) x 8 j-tiles.
  const float scale = 0.08838834764831845f;  // 1/sqrt(128)
#pragma unroll
  for (int i = 0; i < 2; ++i)
#pragma unroll
    for (int r = 0; r < 4; ++r) {
      int t = wave * 32 + i * 16 + quad * 4 + r;
      float mx = -1e30f;
#pragma unroll
      for (int j = 0; j < 8; ++j) {
        int s = j * 16 + colv;
        float v = accs[i][j][r] * scale;
        v = (s <= t) ? v : -1e30f;
        accs[i][j][r] = v;
        mx = fmaxf(mx, v);
      }
#pragma unroll
      for (int off = 1; off < 16; off <<= 1) mx = fmaxf(mx, __shfl_xor(mx, off, 64));
      float l = 0.f;
#pragma unroll
      for (int j = 0; j < 8; ++j) {
        float p = __expf(accs[i][j][r] - mx);
        accs[i][j][r] = p;
        l += p;
      }
#pragma unroll
      for (int off = 1; off < 16; off <<= 1) l += __shfl_xor(l, off, 64);
      float inv = 1.0f / l;
#pragma unroll
      for (int j = 0; j < 8; ++j) {
        int s = j * 16 + colv;
        Qs[t * 128 + ((((s >> 3) ^ (t & 15)) << 3) | (s & 7))] = f2bf(accs[i][j][r] * inv);
      }
    }
  __syncthreads();

  // V -> KVs transposed: KVs[d][s] = V[s][d]
#pragma unroll
  for (int sgi = 0; sgi < 8; ++sgi) {
    int seg = tid + sgi * 256;
    int t = seg >> 4;
    int dg = (seg & 15) << 3;
    uint4 vv = *(const uint4*)(V + gbase + (size_t)t * 2048 + dg);
    const ushort* vp = (const ushort*)&vv;
#pragma unroll
    for (int jj = 0; jj < 8; ++jj) {
      int d = dg + jj;
      KVs[d * 128 + ((((t >> 3) ^ (d & 15)) << 3) | (t & 7))] = vp[jj];
    }
  }
  __syncthreads();

  // O = P V
  floatx4 acco[2][8] = {};
#pragma unroll
  for (int kc = 0; kc < 4; ++kc) {
    bf16x8 af[2], bfr[8];
#pragma unroll
    for (int i = 0; i < 2; ++i) {
      int r = wave * 32 + i * 16 + colv;
      af[i] = *(const bf16x8*)&Qs[r * 128 + ((((kc << 2) | quad) ^ (r & 15)) << 3)];
    }
#pragma unroll
    for (int j = 0; j < 8; ++j) {
      int r = j * 16 + colv;
      bfr[j] = *(const bf16x8*)&KVs[r * 128 + ((((kc << 2) | quad) ^ (r & 15)) << 3)];
    }
#pragma unroll
    for (int i = 0; i < 2; ++i)
#pragma unroll
      for (int j = 0; j < 8; ++j)
        acco[i][j] = __builtin_amdgcn_mfma_f32_16x16x32_bf16(af[i], bfr[j], acco[i][j], 0, 0, 0);
  }

#pragma unroll
  for (int i = 0; i < 2; ++i)
#pragma unroll
    for (int j = 0; j < 8; ++j)
#pragma unroll
      for (int r = 0; r < 4; ++r) {
        int t = wave * 32 + i * 16 + quad * 4 + r;
        int d = j * 16 + colv;
        O[gbase + (size_t)t * 2048 + d] = f2bf(acco[i][j][r]);
      }
}

extern "C" void kernel_launch(void* const* d_in, const int* in_sizes, int n_in,
                              void* d_out, int out_size, void* d_ws, size_t ws_size,
                              hipStream_t stream) {
  const float* x    = (const float*)d_in[0];
  const float* fcos = (const float*)d_in[1];
  const float* fsin = (const float*)d_in[2];
  const float* wq   = (const float*)d_in[3];
  const float* wk   = (const float*)d_in[4];
  const float* wv   = (const float*)d_in[5];
  const float* wo   = (const float*)d_in[6];
  float* out = (float*)d_out;

  const size_t CC = 2048ull * 2048ull;
  const size_t MC = 8192ull * 2048ull;
  ushort* wob = (ushort*)d_ws;
  ushort* xb  = wob + CC;
  ushort* wqb = xb + MC;
  ushort* wkb = wqb + CC;
  ushort* wvb = wkb + CC;
  ushort* Qb  = wvb + CC;
  ushort* Kb  = Qb + MC;
  ushort* Vb  = Kb + MC;

  // one conversion kernel for all five regions: (MC + 4*CC)/4 float4s / 256 thr
  unsigned cvt_blocks = (unsigned)((MC + 4 * CC) / 4 / 256);
  cvt_all<<<dim3(cvt_blocks), 256, 0, stream>>>(x, wq, wk, wv, wo, xb, wqb, wkb, wvb, wob);

  gemm_qkv<<<dim3(64, 16, 3), 256, 0, stream>>>(xb, wqb, wkb, wvb, Qb, Kb, Vb);
  attn_kernel<<<dim3(1024), 256, 0, stream>>>(Qb, Kb, Vb, fcos, fsin, xb /*aliases xb*/);
  gemm_out_k<<<dim3(64, 16), 256, 0, stream>>>(xb, wob, out);
}

// Round 3
// 520.718 us; speedup vs baseline: 1.0574x; 1.0115x over previous
//
#include <hip/hip_runtime.h>
#include <cstdint>

// Attention block: x(B=64,T=128,C=2048) fp32; H=16, hd=128.
// q=x@wq^T, k=x@wk^T, v=x@wv^T ; RoPE(q,k) ; causal softmax attn ; out@wo^T.
// bf16 MFMA; fp32 softmax; RoPE fused into attention kernel.
// R3: XOR bank-swizzle in GEMM LDS tiles (global-side permute, reader-compensated).

typedef unsigned short ushort;
typedef __bf16 bf16x8 __attribute__((ext_vector_type(8)));
typedef float floatx4 __attribute__((ext_vector_type(4)));

__device__ __forceinline__ ushort f2bf(float f) {
  union { float f; uint32_t u; } v; v.f = f;
  uint32_t r = v.u + 0x7FFFu + ((v.u >> 16) & 1u);
  return (ushort)(r >> 16);
}
__device__ __forceinline__ float bf2f(ushort h) {
  union { uint32_t u; float f; } v; v.u = ((uint32_t)h) << 16;
  return v.f;
}

__device__ __forceinline__ void load_lds16(const void* g, void* l) {
  __builtin_amdgcn_global_load_lds(
      (__attribute__((address_space(1))) void*)(uintptr_t)g,
      (__attribute__((address_space(3))) void*)(uint32_t)(uintptr_t)l,
      16, 0, 0);
}

__device__ __forceinline__ void store_out(ushort* C, size_t i, float v) { C[i] = f2bf(v); }
__device__ __forceinline__ void store_out(float* C, size_t i, float v) { C[i] = v; }

// C[m,n] = sum_k A[m,k]*B[n,k].  m97 recipe: 128x128 tile, BK=32, 4 waves, 4x4 acc.
// LDS tile row = 32 elems = 4 k-groups of 16B. Slot (row,g) holds global k-group
// g ^ ((row>>1)&3)  -> a 16-lane read phase touches all 8 four-bank groups
// (2 lanes each = free). Staging applies the same XOR to the global source col.
template <typename OutT>
__device__ __forceinline__ void gemm_bt_body(const ushort* __restrict__ A,
                                             const ushort* __restrict__ B,
                                             OutT* __restrict__ C,
                                             int M, int N, int K) {
  __shared__ __align__(16) ushort As[128 * 32];
  __shared__ __align__(16) ushort Bs[128 * 32];
  const int tid = threadIdx.x;
  const int wave = tid >> 6, lane = tid & 63;
  const int quad = lane >> 4, colv = lane & 15;
  const int m0 = blockIdx.x * 128, n0 = blockIdx.y * 128;
  const int wm = (wave & 1) * 64, wn = (wave >> 1) * 64;

  floatx4 acc[4][4] = {};

  // Staging: thread tid covers LDS slot (row0 = tid>>2, g = tid&3); fetches
  // global k-group g ^ ((row0>>1)&3). (row0+64) has the same XOR (64>>1 % 4 == 0).
  const int row0 = tid >> 2;
  const int gsw = (tid & 3) ^ ((row0 >> 1) & 3);
  const int c0 = gsw * 8;

  // Fragment read addresses (loop-invariant swizzled k-group per row).
  int aoff[4], boff[4];
#pragma unroll
  for (int i = 0; i < 4; ++i) {
    int ra = wm + i * 16 + colv;
    aoff[i] = ra * 32 + ((quad ^ ((ra >> 1) & 3)) << 3);
    int rb = wn + i * 16 + colv;
    boff[i] = rb * 32 + ((quad ^ ((rb >> 1) & 3)) << 3);
  }

  for (int k0 = 0; k0 < K; k0 += 32) {
    if (k0) __syncthreads();
    const ushort* Ab = A + (size_t)(m0 + row0) * K + k0 + c0;
    const ushort* Bb = B + (size_t)(n0 + row0) * K + k0 + c0;
    load_lds16(Ab, &As[wave * 512]);
    load_lds16(Bb, &Bs[wave * 512]);
    load_lds16(Ab + (size_t)64 * K, &As[wave * 512 + 2048]);
    load_lds16(Bb + (size_t)64 * K, &Bs[wave * 512 + 2048]);
    __syncthreads();

    bf16x8 af[4], bfr[4];
#pragma unroll
    for (int i = 0; i < 4; ++i) af[i] = *(const bf16x8*)&As[aoff[i]];
#pragma unroll
    for (int j = 0; j < 4; ++j) bfr[j] = *(const bf16x8*)&Bs[boff[j]];
#pragma unroll
    for (int i = 0; i < 4; ++i)
#pragma unroll
      for (int j = 0; j < 4; ++j)
        acc[i][j] = __builtin_amdgcn_mfma_f32_16x16x32_bf16(af[i], bfr[j], acc[i][j], 0, 0, 0);
  }

#pragma unroll
  for (int i = 0; i < 4; ++i)
#pragma unroll
    for (int j = 0; j < 4; ++j)
#pragma unroll
      for (int r = 0; r < 4; ++r) {
        int m = m0 + wm + i * 16 + quad * 4 + r;
        int n = n0 + wn + j * 16 + colv;
        store_out(C, (size_t)m * N + n, acc[i][j][r]);
      }
}

__global__ __launch_bounds__(256) void gemm_qkv(
    const ushort* __restrict__ A, const ushort* __restrict__ Wq,
    const ushort* __restrict__ Wk, const ushort* __restrict__ Wv,
    ushort* __restrict__ Q, ushort* __restrict__ Kb, ushort* __restrict__ V) {
  const ushort* B = (blockIdx.z == 0) ? Wq : (blockIdx.z == 1) ? Wk : Wv;
  ushort* C = (blockIdx.z == 0) ? Q : (blockIdx.z == 1) ? Kb : V;
  gemm_bt_body<ushort>(A, B, C, 8192, 2048, 2048);
}

__global__ __launch_bounds__(256) void gemm_out_k(
    const ushort* __restrict__ A, const ushort* __restrict__ B,
    float* __restrict__ C) {
  gemm_bt_body<float>(A, B, C, 8192, 2048, 2048);
}

// One kernel converting all five fp32 regions to bf16.
#define NX 4194304u   /* 8192*2048/4 */
#define NW 1048576u   /* 2048*2048/4 */
__global__ void cvt_all(const float* __restrict__ x, const float* __restrict__ wq,
                        const float* __restrict__ wk, const float* __restrict__ wv,
                        const float* __restrict__ wo,
                        ushort* __restrict__ xb, ushort* __restrict__ wqb,
                        ushort* __restrict__ wkb, ushort* __restrict__ wvb,
                        ushort* __restrict__ wob) {
  uint32_t i = blockIdx.x * 256u + threadIdx.x;
  const float* src;
  ushort* dst;
  uint32_t off;
  if (i < NX) {
    src = x; dst = xb; off = i;
  } else {
    uint32_t i2 = i - NX;
    uint32_t r = i2 >> 20;
    off = i2 & (NW - 1u);
    src = (r == 0) ? wq : (r == 1) ? wk : (r == 2) ? wv : wo;
    dst = (r == 0) ? wqb : (r == 1) ? wkb : (r == 2) ? wvb : wob;
  }
  float4 v = ((const float4*)src)[off];
  ushort4 o;
  o.x = f2bf(v.x); o.y = f2bf(v.y); o.z = f2bf(v.z); o.w = f2bf(v.w);
  ((ushort4*)dst)[off] = o;
}

// One block per (b,h). T=128, hd=128. RoPE applied to Q,K on load (fp32 math).
__global__ __launch_bounds__(256) void attn_kernel(
    const ushort* __restrict__ Q, const ushort* __restrict__ K,
    const ushort* __restrict__ V, const float* __restrict__ Cf,
    const float* __restrict__ Sf, ushort* __restrict__ O) {
  __shared__ __align__(16) ushort Qs[128 * 128];   // Q, then P
  __shared__ __align__(16) ushort KVs[128 * 128];  // K, then V^T
  const int b = blockIdx.x >> 4, h = blockIdx.x & 15;
  const int tid = threadIdx.x, wave = tid >> 6, lane = tid & 63;
  const int quad = lane >> 4, colv = lane & 15;
  const size_t gbase = (size_t)b * 262144 + (size_t)h * 128;

#pragma unroll
  for (int sgi = 0; sgi < 8; ++sgi) {
    int seg = tid + sgi * 256;
    int t = seg >> 4, g = seg & 15;
    uint4 qv = *(const uint4*)(Q + gbase + (size_t)t * 2048 + g * 8);
    uint4 kv = *(const uint4*)(K + gbase + (size_t)t * 2048 + g * 8);
    float4 cf = *(const float4*)(Cf + t * 64 + g * 4);
    float4 sf = *(const float4*)(Sf + t * 64 + g * 4);
    uint32_t* qw = (uint32_t*)&qv;
    uint32_t* kw = (uint32_t*)&kv;
#pragma unroll
    for (int j = 0; j < 4; ++j) {
      float c = (&cf.x)[j], s = (&sf.x)[j];
      uint32_t w = qw[j];
      float e = bf2f((ushort)(w & 0xFFFF)), o = bf2f((ushort)(w >> 16));
      qw[j] = (uint32_t)f2bf(e * c - o * s) | ((uint32_t)f2bf(e * s + o * c) << 16);
      w = kw[j];
      e = bf2f((ushort)(w & 0xFFFF)); o = bf2f((ushort)(w >> 16));
      kw[j] = (uint32_t)f2bf(e * c - o * s) | ((uint32_t)f2bf(e * s + o * c) << 16);
    }
    int so = t * 128 + ((g ^ (t & 15)) << 3);
    *(uint4*)&Qs[so] = qv;
    *(uint4*)&KVs[so] = kv;
  }
  __syncthreads();

  floatx4 accs[2][8] = {};
#pragma unroll
  for (int kc = 0; kc < 4; ++kc) {
    bf16x8 af[2], bfr[8];
#pragma unroll
    for (int i = 0; i < 2; ++i) {
      int r = wave * 32 + i * 16 + colv;
      af[i] = *(const bf16x8*)&Qs[r * 128 + ((((kc << 2) | quad) ^ (r & 15)) << 3)];
    }
#pragma unroll
    for (int j = 0; j < 8; ++j) {
      int r = j * 16 + colv;
      bfr[j] = *(const bf16x8*)&KVs[r * 128 + ((((kc << 2) | quad) ^ (r & 15)) << 3)];
    }
#pragma unroll
    for (int i = 0; i < 2; ++i)
#pragma unroll
      for (int j = 0; j < 8; ++j)
        accs[i][j] = __builtin_amdgcn_mfma_f32_16x16x32_bf16(af[i], bfr[j], accs[i][j], 0, 0, 0);
  }

  const float scale = 0.08838834764831845f;  // 1/sqrt(128)
#pragma unroll
  for (int i = 0; i < 2; ++i)
#pragma unroll
    for (int r = 0; r < 4; ++r) {
      int t = wave * 32 + i * 16 + quad * 4 + r;
      float mx = -1e30f;
#pragma unroll
      for (int j = 0; j < 8; ++j) {
        int s = j * 16 + colv;
        float v = accs[i][j][r] * scale;
        v = (s <= t) ? v : -1e30f;
        accs[i][j][r] = v;
        mx = fmaxf(mx, v);
      }
#pragma unroll
      for (int off = 1; off < 16; off <<= 1) mx = fmaxf(mx, __shfl_xor(mx, off, 64));
      float l = 0.f;
#pragma unroll
      for (int j = 0; j < 8; ++j) {
        float p = __expf(accs[i][j][r] - mx);
        accs[i][j][r] = p;
        l += p;
      }
#pragma unroll
      for (int off = 1; off < 16; off <<= 1) l += __shfl_xor(l, off, 64);
      float inv = 1.0f / l;
#pragma unroll
      for (int j = 0; j < 8; ++j) {
        int s = j * 16 + colv;
        Qs[t * 128 + ((((s >> 3) ^ (t & 15)) << 3) | (s & 7))] = f2bf(accs[i][j][r] * inv);
      }
    }
  __syncthreads();

#pragma unroll
  for (int sgi = 0; sgi < 8; ++sgi) {
    int seg = tid + sgi * 256;
    int t = seg >> 4;
    int dg = (seg & 15) << 3;
    uint4 vv = *(const uint4*)(V + gbase + (size_t)t * 2048 + dg);
    const ushort* vp = (const ushort*)&vv;
#pragma unroll
    for (int jj = 0; jj < 8; ++jj) {
      int d = dg + jj;
      KVs[d * 128 + ((((t >> 3) ^ (d & 15)) << 3) | (t & 7))] = vp[jj];
    }
  }
  __syncthreads();

  floatx4 acco[2][8] = {};
#pragma unroll
  for (int kc = 0; kc < 4; ++kc) {
    bf16x8 af[2], bfr[8];
#pragma unroll
    for (int i = 0; i < 2; ++i) {
      int r = wave * 32 + i * 16 + colv;
      af[i] = *(const bf16x8*)&Qs[r * 128 + ((((kc << 2) | quad) ^ (r & 15)) << 3)];
    }
#pragma unroll
    for (int j = 0; j < 8; ++j) {
      int r = j * 16 + colv;
      bfr[j] = *(const bf16x8*)&KVs[r * 128 + ((((kc << 2) | quad) ^ (r & 15)) << 3)];
    }
#pragma unroll
    for (int i = 0; i < 2; ++i)
#pragma unroll
      for (int j = 0; j < 8; ++j)
        acco[i][j] = __builtin_amdgcn_mfma_f32_16x16x32_bf16(af[i], bfr[j], acco[i][j], 0, 0, 0);
  }

#pragma unroll
  for (int i = 0; i < 2; ++i)
#pragma unroll
    for (int j = 0; j < 8; ++j)
#pragma unroll
      for (int r = 0; r < 4; ++r) {
        int t = wave * 32 + i * 16 + quad * 4 + r;
        int d = j * 16 + colv;
        O[gbase + (size_t)t * 2048 + d] = f2bf(acco[i][j][r]);
      }
}

extern "C" void kernel_launch(void* const* d_in, const int* in_sizes, int n_in,
                              void* d_out, int out_size, void* d_ws, size_t ws_size,
                              hipStream_t stream) {
  const float* x    = (const float*)d_in[0];
  const float* fcos = (const float*)d_in[1];
  const float* fsin = (const float*)d_in[2];
  const float* wq   = (const float*)d_in[3];
  const float* wk   = (const float*)d_in[4];
  const float* wv   = (const float*)d_in[5];
  const float* wo   = (const float*)d_in[6];
  float* out = (float*)d_out;

  const size_t CC = 2048ull * 2048ull;
  const size_t MC = 8192ull * 2048ull;
  ushort* wob = (ushort*)d_ws;
  ushort* xb  = wob + CC;
  ushort* wqb = xb + MC;
  ushort* wkb = wqb + CC;
  ushort* wvb = wkb + CC;
  ushort* Qb  = wvb + CC;
  ushort* Kb  = Qb + MC;
  ushort* Vb  = Kb + MC;

  unsigned cvt_blocks = (unsigned)((MC + 4 * CC) / 4 / 256);
  cvt_all<<<dim3(cvt_blocks), 256, 0, stream>>>(x, wq, wk, wv, wo, xb, wqb, wkb, wvb, wob);

  gemm_qkv<<<dim3(64, 16, 3), 256, 0, stream>>>(xb, wqb, wkb, wvb, Qb, Kb, Vb);
  attn_kernel<<<dim3(1024), 256, 0, stream>>>(Qb, Kb, Vb, fcos, fsin, xb);
  gemm_out_k<<<dim3(64, 16), 256, 0, stream>>>(xb, wob, out);
}